// Round 9
// baseline (210.896 us; speedup 1.0000x reference)
//
#include <hip/hip_runtime.h>

// Factored single-row attention (reference returns out[:, -1, :] only).
// ws layout (floats): M2p [0,65536) packed [k4][e][4]; Wvp [65536,131072)
// packed [d4][e][4]; v0 @131072; c @131328; w1 @131584; w2 @131840;
// dconst {sum(bk), bq.bk, sum(bq)} (3 doubles) @132096.
//   M2[f][d] = sum_e Wq[e][f] Wk[e][d]  (u = td*(x49@M2) + v0)
//   v0[d] = sum_e bq[e] Wk[e][d];  c[d] = sum_e Wk[e][d]
//   w1[f] = sum_e bk[e] Wq[e][f];  w2[f] = sum_e Wq[e][f]
// Score paths (identical to all passing rounds):
//   q-kept & s-kept : (xs_s.u + q.bk)/16   q-kept & s-mask: NEG*sum(q)/16
//   q-mask & s-kept : NEG*(xs_s.c + sum(bk))/16   both: 256e10/16
// Round-16: r15's lane-per-row attnk failed because kP=255 < row length 256
// -- element (s,255) aliased (s+1,0): staging race + corrupt reads (absmax
// 0.15). Fix: kP=257 (>=256, odd). bank(s,d)=(s+d)%32:
//   score phase (uniform d, s=lane): xL 2-way (free), vL wave-uniform ->
//     broadcast (free) -- rotation dropped, strictly better than r15;
//   PV phase (uniform s, d=tid): consecutive d -> conflict-free.
// Everything else verbatim from r15 (r14-proven structure):
//   ukernel (512x512): U=X49@M2+v0 -> d_out. attnk (2048x256): lane-per-row,
//   3 barriers, ONE softmax butterfly pair per batch. okernel (512x512):
//   OUT=Y@WvT+bv in-place on d_out.

namespace {
constexpr int kB = 2048;
constexpr int kT = 50;
constexpr int kD = 256;
constexpr double kNeg = -100000.0;
constexpr int oM2 = 0;
constexpr int oWvp = 65536;
constexpr int oV0 = 131072;
constexpr int oC = 131328;
constexpr int oW1 = 131584;
constexpr int oW2 = 131840;
constexpr int oDbl = 132096;  // 3 doubles
constexpr int kP = 257;  // LDS pitch: >= kD, odd -> bank(s,d)=(s+d)%32
}  // namespace

// ---------------- precomp: VERBATIM from rounds 5-15 (proven) -------------
__global__ __launch_bounds__(256) void precomp(
    const float* __restrict__ Wq, const float* __restrict__ bq,
    const float* __restrict__ Wk, const float* __restrict__ bk,
    const float* __restrict__ Wv, float* __restrict__ ws) {
  const int t = threadIdx.x;
  const int wave = t >> 6;
  const int lane = t & 63;
  const int blk = blockIdx.x;
  __shared__ float coefL[kD];
  __shared__ double red[3][4];

  if (blk < 256) {
    const int a = blk;
    coefL[t] = Wq[(size_t)t * kD + a];
    __syncthreads();
    const float* kcol = Wk + t;
    float pre[8];
#pragma unroll
    for (int k = 0; k < 8; ++k) pre[k] = kcol[(size_t)k * kD];
    float acc = 0.f;
    for (int j0 = 0; j0 < kD; j0 += 8) {
      float cur[8];
#pragma unroll
      for (int k = 0; k < 8; ++k) cur[k] = pre[k];
      const int nx = (j0 + 8 < kD) ? (j0 + 8) : 0;
#pragma unroll
      for (int k = 0; k < 8; ++k) pre[k] = kcol[(size_t)(nx + k) * kD];
#pragma unroll
      for (int k = 0; k < 8; ++k) acc += coefL[j0 + k] * cur[k];
    }
    ws[oM2 + (a >> 2) * 1024 + 4 * t + (a & 3)] = acc;
  } else if (blk < 258) {
    const float* W = (blk == 256) ? Wk : Wq;
    const float* coef = (blk == 256) ? bq : bk;
    coefL[t] = coef[t];
    __syncthreads();
    const float* col = W + t;
    float pre[8];
#pragma unroll
    for (int k = 0; k < 8; ++k) pre[k] = col[(size_t)k * kD];
    double a0 = 0.0, a1 = 0.0;
    for (int j0 = 0; j0 < kD; j0 += 8) {
      float cur[8];
#pragma unroll
      for (int k = 0; k < 8; ++k) cur[k] = pre[k];
      const int nx = (j0 + 8 < kD) ? (j0 + 8) : 0;
#pragma unroll
      for (int k = 0; k < 8; ++k) pre[k] = col[(size_t)(nx + k) * kD];
#pragma unroll
      for (int k = 0; k < 8; ++k) {
        const double w = (double)cur[k];
        a0 += (double)coefL[j0 + k] * w;
        a1 += w;
      }
    }
    if (blk == 256) {
      ws[oV0 + t] = (float)a0;
      ws[oC + t] = (float)a1;
    } else {
      ws[oW1 + t] = (float)a0;
      ws[oW2 + t] = (float)a1;
      double p0 = (double)bk[t];
      double p1 = (double)bq[t] * (double)bk[t];
      double p2 = (double)bq[t];
#pragma unroll
      for (int off = 32; off; off >>= 1) {
        p0 += __shfl_xor(p0, off);
        p1 += __shfl_xor(p1, off);
        p2 += __shfl_xor(p2, off);
      }
      if (lane == 0) {
        red[0][wave] = p0;
        red[1][wave] = p1;
        red[2][wave] = p2;
      }
      __syncthreads();
      if (t == 0) {
        double* dcw = (double*)(ws + oDbl);
        dcw[0] = red[0][0] + red[0][1] + red[0][2] + red[0][3];
        dcw[1] = red[1][0] + red[1][1] + red[1][2] + red[1][3];
        dcw[2] = red[2][0] + red[2][1] + red[2][2] + red[2][3];
      }
    }
  } else {
    const int d4b = (blk - 258) * 4;
    float4 in[4];
#pragma unroll
    for (int k = 0; k < 4; ++k)
      in[k] = *(const float4*)(Wv + (size_t)t * kD + 4 * (d4b + k));
    float4* Wvp = (float4*)(ws + oWvp);
#pragma unroll
    for (int k = 0; k < 4; ++k) Wvp[(size_t)(d4b + k) * kD + t] = in[k];
  }
}

// ---- K1: U = X49 @ M2 + v0 -> uout (d_out scratch). r12/r14 verbatim. ----
__global__ __launch_bounds__(512) void ukernel(
    const float* __restrict__ x, const float* __restrict__ td,
    const float* __restrict__ ws, float* __restrict__ uout) {
  const int tid = threadIdx.x;
  const int lane = tid & 63;
  const int w = tid >> 6;
  const int b0 = blockIdx.x * 4;
  __shared__ __align__(16) float xsL[4][kD];
  __shared__ __align__(16) float scr[2][4][kD];
  const float4* M2v = (const float4*)(ws + oM2);

  if (w < 4) {
    const int b = b0 + w;
    const float tdl = td[(size_t)b * kT + kT - 1];
    const float4 xv =
        ((const float4*)(x + ((size_t)b * kT + kT - 1) * kD))[lane];
    float4 xs;
    xs.x = xv.x * tdl; xs.y = xv.y * tdl;
    xs.z = xv.z * tdl; xs.w = xv.w * tdl;
    *(float4*)(&xsL[w][4 * lane]) = xs;
  }
  __syncthreads();

  {
    const int gU = w & 3;
    const int kh = w >> 2;
    const int col = 64 * gU + lane;
    const int kb = kh * 32;
    float4 A = M2v[(size_t)(kb + 0) * 256 + col];
    float4 B = M2v[(size_t)(kb + 1) * 256 + col];
    float4 C = M2v[(size_t)(kb + 2) * 256 + col];
    float4 D = M2v[(size_t)(kb + 3) * 256 + col];
    float acc[4] = {0.f, 0.f, 0.f, 0.f};
    for (int k4 = kb; k4 < kb + 32; k4 += 2) {
      const float4 c0 = A, c1 = B;
      A = C;
      B = D;
      const int n0 = (k4 + 4 < kb + 32) ? k4 + 4 : kb;
      const int n1 = (k4 + 5 < kb + 32) ? k4 + 5 : kb;
      C = M2v[(size_t)n0 * 256 + col];
      D = M2v[(size_t)n1 * 256 + col];
#pragma unroll
      for (int jb = 0; jb < 4; ++jb) {
        const float4 x0 = *(const float4*)(&xsL[jb][4 * k4]);
        const float4 x1 = *(const float4*)(&xsL[jb][4 * (k4 + 1)]);
        acc[jb] += x0.x * c0.x + x0.y * c0.y + x0.z * c0.z + x0.w * c0.w +
                   x1.x * c1.x + x1.y * c1.y + x1.z * c1.z + x1.w * c1.w;
      }
    }
#pragma unroll
    for (int jb = 0; jb < 4; ++jb) scr[kh][jb][col] = acc[jb];
  }
  __syncthreads();

#pragma unroll
  for (int rr = 0; rr < 2; ++rr) {
    const int idx = tid + rr * 512;
    const int mj = idx >> 8;
    const int mcol = idx & 255;
    uout[(size_t)(b0 + mj) * kD + mcol] =
        scr[0][mj][mcol] + scr[1][mj][mcol] + ws[oV0 + mcol];
  }
}

// ---- K2: attention, lane-per-row. 1 batch/block, 256 threads. Reads U
//      from uy (d_out), overwrites the row with Y. 3 barriers, zero
//      per-iteration cross-lane ops. ----
__global__ __launch_bounds__(256) void attnk(
    const float* __restrict__ x, const int* __restrict__ mask,
    const float* __restrict__ td, const float* __restrict__ ws,
    float* __restrict__ uy) {
  const int tid = threadIdx.x;
  const int lane = tid & 63;
  const int w = tid >> 6;
  const int b = blockIdx.x;
  __shared__ __align__(16) float xL[kT * kP + 4];  // ~51.4 KB, pitch 257
  __shared__ float vL[kD];
  __shared__ float pL[4][64];
  __shared__ float wL[64];

  const float* xb = x + (size_t)b * kT * kD;
  const int mqg = mask[(size_t)b * kT + (kT - 1)];

  // ---- stage x tile (b128 global -> 4x b32 LDS) + v vector ----
  {
    const float4* xv4 = (const float4*)xb;
#pragma unroll
    for (int k = 0; k < 13; ++k) {
      const int idx4 = tid + 256 * k;
      if (idx4 < kT * 64) {
        const int s = idx4 >> 6;
        const int d4 = idx4 & 63;
        const float4 v = xv4[idx4];
        float* dst = &xL[s * kP + 4 * d4];
        dst[0] = v.x; dst[1] = v.y; dst[2] = v.z; dst[3] = v.w;
      }
    }
    vL[tid] = mqg ? uy[(size_t)b * kD + tid] : ws[oC + tid];
  }

  // per-lane row scalars (lane == s)
  const float mtd = (lane < kT) ? td[(size_t)b * kT + lane] : 0.f;
  const int mmk = (lane < kT) ? mask[(size_t)b * kT + lane] : 0;

  // ---- wave-0 prologue: fp64 scalars (verbatim math) ----
  double Qb = 0.0, Sq = 0.0;
  if (w == 0) {
    const double* dc = (const double*)(ws + oDbl);
    const float tdl = __shfl(mtd, kT - 1);
    const float4 a1 = ((const float4*)(ws + oW1))[lane];
    const float4 a2 = ((const float4*)(ws + oW2))[lane];
    const float4 xv = ((const float4*)(xb + (size_t)(kT - 1) * kD))[lane];
    double s1 = (double)xv.x * a1.x + (double)xv.y * a1.y +
                (double)xv.z * a1.z + (double)xv.w * a1.w;
    double s2 = (double)xv.x * a2.x + (double)xv.y * a2.y +
                (double)xv.z * a2.z + (double)xv.w * a2.w;
#pragma unroll
    for (int off = 32; off; off >>= 1) {
      s1 += __shfl_xor(s1, off);
      s2 += __shfl_xor(s2, off);
    }
    Qb = (double)tdl * s1 + dc[1];
    Sq = (double)tdl * s2 + dc[2];
  }
  __syncthreads();

  // ---- partial scores: wave w covers d in [64w,64w+64); lane = row s.
  //      d uniform across lanes: vL -> broadcast (free); xL bank =
  //      (s+d)%32 -> 2-way across 64 lanes (free). ----
  {
    const int srow = (lane < kT) ? lane : 0;  // clamp: garbage rows unused
    const float* xrow = &xL[srow * kP];
    const int dbase = 64 * w;
    float acc0 = 0.f, acc1 = 0.f;
#pragma unroll
    for (int t = 0; t < 64; t += 2) {
      acc0 += xrow[dbase + t] * vL[dbase + t];
      acc1 += xrow[dbase + t + 1] * vL[dbase + t + 1];
    }
    pL[w][lane] = acc0 + acc1;
  }
  __syncthreads();

  // ---- wave-0 finish: combine partials, score (verbatim fp64 paths),
  //      single softmax across lanes, fold td into weights ----
  if (w == 0) {
    const double* dc = (const double*)(ws + oDbl);
    const float praw = pL[0][lane] + pL[1][lane] + pL[2][lane] + pL[3][lane];
    const float pfull = praw * mtd;  // p_s = td_s * (x_s . v)
    const double Cm = kNeg * Sq * 0.0625;
    const double sbkd = dc[0];
    const double Cbb = 256.0 * 1.0e10 * 0.0625;
    double sc;
    if (lane < kT) {
      if (mqg)
        sc = mmk ? ((double)pfull + Qb) * 0.0625 : Cm;
      else
        sc = mmk ? kNeg * ((double)pfull + sbkd) * 0.0625 : Cbb;
    } else {
      sc = -1.0e300;
    }
    double m = sc;
#pragma unroll
    for (int off = 32; off; off >>= 1) {
      const double o = __shfl_xor(m, off);
      if (o > m) m = o;
    }
    const float e = __expf((float)(sc - m));
    float l = e;
#pragma unroll
    for (int off = 32; off; off >>= 1) l += __shfl_xor(l, off);
    wL[lane] = e * (1.0f / l) * mtd;  // w_s/l * td_s (0 for lanes >= kT)
  }
  __syncthreads();

  // ---- PV: thread d accumulates y_d = sum_s wL[s]*x[s][d]; wL broadcast,
  //      xL conflict-free (lanes d consecutive, bank (s+d)%32). ----
  {
    const int d = tid;
    float y0 = 0.f, y1 = 0.f;
#pragma unroll
    for (int s = 0; s < kT; s += 2) {
      y0 += wL[s] * xL[s * kP + d];
      y1 += wL[s + 1] * xL[(s + 1) * kP + d];
    }
    uy[(size_t)b * kD + d] = y0 + y1;
  }
}

// ---- K3: OUT = Y @ Wv^T + bv, in-place on io (d_out). r12/r14 verbatim. --
__global__ __launch_bounds__(512) void okernel(
    const float* __restrict__ bv, const float* __restrict__ ws,
    float* __restrict__ io) {
  const int tid = threadIdx.x;
  const int lane = tid & 63;
  const int w = tid >> 6;
  const int b0 = blockIdx.x * 4;
  __shared__ __align__(16) float yL[4][kD];
  __shared__ __align__(16) float scr[2][4][kD];
  const float4* Wvv = (const float4*)(ws + oWvp);

#pragma unroll
  for (int rr = 0; rr < 2; ++rr) {
    const int idx = tid + rr * 512;
    const int mj = idx >> 8;
    const int mcol = idx & 255;
    yL[mj][mcol] = io[(size_t)(b0 + mj) * kD + mcol];
  }
  __syncthreads();

  {
    const int gU = w & 3;
    const int kh = w >> 2;
    const int col = 64 * gU + lane;
    const int kb = kh * 32;
    float4 A = Wvv[(size_t)(kb + 0) * 256 + col];
    float4 B = Wvv[(size_t)(kb + 1) * 256 + col];
    float4 C = Wvv[(size_t)(kb + 2) * 256 + col];
    float4 D = Wvv[(size_t)(kb + 3) * 256 + col];
    float acc[4] = {0.f, 0.f, 0.f, 0.f};
    for (int k4 = kb; k4 < kb + 32; k4 += 2) {
      const float4 c0 = A, c1 = B;
      A = C;
      B = D;
      const int n0 = (k4 + 4 < kb + 32) ? k4 + 4 : kb;
      const int n1 = (k4 + 5 < kb + 32) ? k4 + 5 : kb;
      C = Wvv[(size_t)n0 * 256 + col];
      D = Wvv[(size_t)n1 * 256 + col];
#pragma unroll
      for (int jb = 0; jb < 4; ++jb) {
        const float4 y0 = *(const float4*)(&yL[jb][4 * k4]);
        const float4 y1 = *(const float4*)(&yL[jb][4 * (k4 + 1)]);
        acc[jb] += y0.x * c0.x + y0.y * c0.y + y0.z * c0.z + y0.w * c0.w +
                   y1.x * c1.x + y1.y * c1.y + y1.z * c1.z + y1.w * c1.w;
      }
    }
#pragma unroll
    for (int jb = 0; jb < 4; ++jb) scr[kh][jb][col] = acc[jb];
  }
  __syncthreads();

#pragma unroll
  for (int rr = 0; rr < 2; ++rr) {
    const int idx = tid + rr * 512;
    const int mj = idx >> 8;
    const int mcol = idx & 255;
    io[(size_t)(b0 + mj) * kD + mcol] =
        scr[0][mj][mcol] + scr[1][mj][mcol] + bv[mcol];
  }
}

extern "C" void kernel_launch(void* const* d_in, const int* in_sizes, int n_in,
                              void* d_out, int out_size, void* d_ws,
                              size_t ws_size, hipStream_t stream) {
  const float* x = (const float*)d_in[0];
  const int* mask = (const int*)d_in[1];
  const float* td = (const float*)d_in[2];
  const float* Wq = (const float*)d_in[3];
  const float* bq = (const float*)d_in[4];
  const float* Wk = (const float*)d_in[5];
  const float* bk = (const float*)d_in[6];
  const float* Wv = (const float*)d_in[7];
  const float* bv = (const float*)d_in[8];
  float* ws = (float*)d_ws;  // ~530 KB used
  float* out = (float*)d_out;  // also serves as U/Y scratch (2 MB)
  (void)in_sizes; (void)n_in; (void)out_size; (void)ws_size;

  hipLaunchKernelGGL(precomp, dim3(274), dim3(256), 0, stream, Wq, bq, Wk, bk,
                     Wv, ws);
  hipLaunchKernelGGL(ukernel, dim3(kB / 4), dim3(512), 0, stream, x, td,
                     (const float*)ws, out);
  hipLaunchKernelGGL(attnk, dim3(kB), dim3(256), 0, stream, x, mask, td,
                     (const float*)ws, out);
  hipLaunchKernelGGL(okernel, dim3(kB / 4), dim3(512), 0, stream, bv,
                     (const float*)ws, out);
}